// Round 5
// baseline (50.190 us; speedup 1.0000x reference)
//
#include <hip/hip_runtime.h>
#include <math.h>

// out[r, v] = sin(x[r] * freqs[v]),  r in [0, 64*4096), v in [0, 256)
// freqs[v] = 10^(min(v,127)/127 * 4)
//
// One wave per 8 rows: two float4 broadcast-loads of x cover 8 rows; lane l
// covers v = 4l..4l+3 and does one 16B cached store per row
// (64 lanes * 16 B = 1024 B contiguous per row; 8 KiB contiguous per group).
// sin via hardware v_sin_f32 (revolution input): c[v] = freqs[v]/(2*pi)
// precomputed in f64 per thread.
// R3 lesson: nontemporal stores REGRESSED (54.2 vs 49.9 us) -- keep cached.
// R4 lesson: 4-row unroll + cached = 46.8 us; this round: 8-row unroll to
// deepen the per-wave store pipeline.

typedef float f32x4 __attribute__((ext_vector_type(4)));

__global__ __launch_bounds__(256) void InputLayer_57337813401914_kernel(
    const float* __restrict__ x, float* __restrict__ out, int rows) {
  const int lane = threadIdx.x & 63;
  const int gwave = (int)((blockIdx.x * blockDim.x + threadIdx.x) >> 6);
  const int nwaves = (int)((gridDim.x * blockDim.x) >> 6);

  // Per-thread frequency constants (freq / 2pi), computed once in f64.
  float c[4];
#pragma unroll
  for (int j = 0; j < 4; ++j) {
    int v = 4 * lane + j;
    int idx = v < 128 ? v : 127;
    double e = (double)idx * (4.0 / 127.0);
    double f = pow(10.0, e);
    c[j] = (float)(f * 0.15915494309189535);  // f / (2*pi)
  }

  const int ngroups = rows >> 3;  // 8 rows per group
  for (int g = gwave; g < ngroups; g += nwaves) {
    // All 64 lanes load the same 32 B -> broadcast; covers rows 8g..8g+7.
    const f32x4* xp = reinterpret_cast<const f32x4*>(x + (size_t)g * 8);
    f32x4 xq0 = xp[0];
    f32x4 xq1 = xp[1];
    float* base = out + ((size_t)g * 8) * 256 + (size_t)lane * 4;
#pragma unroll
    for (int k = 0; k < 8; ++k) {
      float xv = (k < 4) ? xq0[k & 3] : xq1[k & 3];  // static after unroll
      f32x4 o;
      o.x = __builtin_amdgcn_sinf(__builtin_amdgcn_fractf(xv * c[0]));
      o.y = __builtin_amdgcn_sinf(__builtin_amdgcn_fractf(xv * c[1]));
      o.z = __builtin_amdgcn_sinf(__builtin_amdgcn_fractf(xv * c[2]));
      o.w = __builtin_amdgcn_sinf(__builtin_amdgcn_fractf(xv * c[3]));
      *reinterpret_cast<f32x4*>(base + (size_t)k * 256) = o;
    }
  }
}

extern "C" void kernel_launch(void* const* d_in, const int* in_sizes, int n_in,
                              void* d_out, int out_size, void* d_ws, size_t ws_size,
                              hipStream_t stream) {
  const float* x = (const float*)d_in[0];
  float* out = (float*)d_out;
  const int rows = in_sizes[0];  // 64 * 4096 = 262144

  const int block = 256;
  const int grid = 2048;  // 8192 waves (full residency); 32768 groups -> 4/wave
  InputLayer_57337813401914_kernel<<<grid, block, 0, stream>>>(x, out, rows);
}

// Round 6
// 49.902 us; speedup vs baseline: 1.0058x; 1.0058x over previous
//
#include <hip/hip_runtime.h>
#include <math.h>

// out[r, v] = sin(x[r] * freqs[v]),  r in [0, 64*4096), v in [0, 256)
// freqs[v] = 10^(min(v,127)/127 * 4)
//
// R4 best so far: 46.8 us (4-row groups, cached stores, grid-stride, 100% occ).
// R5 (8-row) regressed: 50.2. R3 (nontemporal) regressed: 54.2.
// This round: fill-kernel-like shape -- LOW occupancy (grid=512 -> 2 waves/SIMD,
// like rocclr fill's ~10% occ @ 7.0 TB/s) + CONTIGUOUS per-wave ownership
// (each wave writes a 128 KiB sequential stream instead of scattered 4 KiB
// grid-stride chunks).

typedef float f32x4 __attribute__((ext_vector_type(4)));

__global__ __launch_bounds__(256) void InputLayer_57337813401914_kernel(
    const float* __restrict__ x, float* __restrict__ out, int rows) {
  const int lane = threadIdx.x & 63;
  const int gwave = (int)((blockIdx.x * blockDim.x + threadIdx.x) >> 6);
  const int nwaves = (int)((gridDim.x * blockDim.x) >> 6);

  // Per-thread frequency constants (freq / 2pi), computed once in f64.
  float c[4];
#pragma unroll
  for (int j = 0; j < 4; ++j) {
    int v = 4 * lane + j;
    int idx = v < 128 ? v : 127;
    double e = (double)idx * (4.0 / 127.0);
    double f = pow(10.0, e);
    c[j] = (float)(f * 0.15915494309189535);  // f / (2*pi)
  }

  const int ngroups = rows >> 2;  // 4 rows per group (65536 groups)
  // Contiguous ownership: wave w handles groups [w*gpw, (w+1)*gpw).
  const int gpw = ngroups / nwaves;            // 32 for grid=512
  const int gbeg = gwave * gpw;
  const int gend = (gbeg + gpw < ngroups) ? gbeg + gpw : ngroups;

#pragma unroll 1
  for (int g = gbeg; g < gend; ++g) {
    // All 64 lanes load the same 16 B -> broadcast; covers rows 4g..4g+3.
    f32x4 xq = *reinterpret_cast<const f32x4*>(x + (size_t)g * 4);
    float* base = out + ((size_t)g * 4) * 256 + (size_t)lane * 4;
#pragma unroll
    for (int k = 0; k < 4; ++k) {
      float xv = xq[k];  // static index (unrolled) -> stays in registers
      f32x4 o;
      o.x = __builtin_amdgcn_sinf(__builtin_amdgcn_fractf(xv * c[0]));
      o.y = __builtin_amdgcn_sinf(__builtin_amdgcn_fractf(xv * c[1]));
      o.z = __builtin_amdgcn_sinf(__builtin_amdgcn_fractf(xv * c[2]));
      o.w = __builtin_amdgcn_sinf(__builtin_amdgcn_fractf(xv * c[3]));
      *reinterpret_cast<f32x4*>(base + (size_t)k * 256) = o;
    }
  }
}

extern "C" void kernel_launch(void* const* d_in, const int* in_sizes, int n_in,
                              void* d_out, int out_size, void* d_ws, size_t ws_size,
                              hipStream_t stream) {
  const float* x = (const float*)d_in[0];
  float* out = (float*)d_out;
  const int rows = in_sizes[0];  // 64 * 4096 = 262144

  const int block = 256;
  const int grid = 512;  // 2048 waves; 32 contiguous groups (128 KiB) per wave
  InputLayer_57337813401914_kernel<<<grid, block, 0, stream>>>(x, out, rows);
}

// Round 7
// 47.043 us; speedup vs baseline: 1.0669x; 1.0608x over previous
//
#include <hip/hip_runtime.h>
#include <math.h>

// out[r, v] = sin(x[r] * freqs[v]),  r in [0, 64*4096), v in [0, 256)
// freqs[v] = 10^(min(v,127)/127 * 4)
//
// R4 best: 46.8 us (4-row groups, cached f32x4 stores, grid-stride, full occ).
// Failed: NT stores (54.2), 8-row unroll (50.2), low-occ contiguous (49.9).
//
// This round: PREFETCH the next group's x BEFORE this group's stores.
// Rationale: vmcnt is in-order and counts stores; load-after-stores forces a
// full vmcnt(0) drain of the previous 4 stores before each group's compute.
// Issuing the next load first lets the compiler wait with vmcnt(4) (stores
// still in flight) -- the T4 "counted vmcnt, never 0" mechanism.

typedef float f32x4 __attribute__((ext_vector_type(4)));

__global__ __launch_bounds__(256) void InputLayer_57337813401914_kernel(
    const float* __restrict__ x, float* __restrict__ out, int rows) {
  const int lane = threadIdx.x & 63;
  const int gwave = (int)((blockIdx.x * blockDim.x + threadIdx.x) >> 6);
  const int nwaves = (int)((gridDim.x * blockDim.x) >> 6);

  // Per-thread frequency constants (freq / 2pi), computed once in f64.
  float c[4];
#pragma unroll
  for (int j = 0; j < 4; ++j) {
    int v = 4 * lane + j;
    int idx = v < 128 ? v : 127;
    double e = (double)idx * (4.0 / 127.0);
    double f = pow(10.0, e);
    c[j] = (float)(f * 0.15915494309189535);  // f / (2*pi)
  }

  const int ngroups = rows >> 2;  // 4 rows per group
  int g = gwave;
  if (g >= ngroups) return;

  // Prologue: load this wave's first x quad (broadcast, 16 B).
  f32x4 xq = *reinterpret_cast<const f32x4*>(x + (size_t)g * 4);

  for (;;) {
    const int gn = g + nwaves;
    const bool has_next = gn < ngroups;  // wave-uniform branch
    f32x4 xq_next;
    if (has_next) {
      // Issue next group's load BEFORE this group's stores -> the wait for
      // xq_next in the next iteration is a counted vmcnt, not a drain.
      xq_next = *reinterpret_cast<const f32x4*>(x + (size_t)gn * 4);
    }

    float* base = out + ((size_t)g * 4) * 256 + (size_t)lane * 4;
#pragma unroll
    for (int k = 0; k < 4; ++k) {
      float xv = xq[k];  // static index (unrolled) -> stays in registers
      f32x4 o;
      o.x = __builtin_amdgcn_sinf(__builtin_amdgcn_fractf(xv * c[0]));
      o.y = __builtin_amdgcn_sinf(__builtin_amdgcn_fractf(xv * c[1]));
      o.z = __builtin_amdgcn_sinf(__builtin_amdgcn_fractf(xv * c[2]));
      o.w = __builtin_amdgcn_sinf(__builtin_amdgcn_fractf(xv * c[3]));
      *reinterpret_cast<f32x4*>(base + (size_t)k * 256) = o;
    }

    if (!has_next) break;
    xq = xq_next;
    g = gn;
  }
}

extern "C" void kernel_launch(void* const* d_in, const int* in_sizes, int n_in,
                              void* d_out, int out_size, void* d_ws, size_t ws_size,
                              hipStream_t stream) {
  const float* x = (const float*)d_in[0];
  float* out = (float*)d_out;
  const int rows = in_sizes[0];  // 64 * 4096 = 262144

  const int block = 256;
  const int grid = 2048;  // 8192 waves (full residency); 8 groups per wave
  InputLayer_57337813401914_kernel<<<grid, block, 0, stream>>>(x, out, rows);
}